// Round 1
// baseline (1369.372 us; speedup 1.0000x reference)
//
#include <hip/hip_runtime.h>
#include <math.h>

#define WS_    3
#define GRID_  4
#define HW_    9
#define HEADS_ 4
#define HD_    16
#define DIM_   64
#define OC_    192      // 3*INNER
#define P_     81       // HW*HW
#define BATCH_ 8192

#define BLOCK_ 512
#define BPB_   4
#define NBLK_  (BATCH_/BPB_)   // 2048

// LDS row pads (floats). 66 -> 33 banks/row (odd): conflict-friendly for float2.
#define PW_  66
#define PW1_ 66
#define PW2_ 34
#define PX_  66
#define PQ_  196   // multiple of 4 -> float4-aligned rows
#define PH_  34

struct alignas(16) Smem {
    float QKV[P_ * PQ_];    // 15876 f  (reused as H1[81*34] later)
    float X  [P_ * PX_];    //  5346 f  (reused as canvas)
    float W  [OC_ * PW_];   // 12672 f
    float W1 [32 * PW1_];   //  2112 f
    float W2 [64 * PW2_];   //  2176 f
    float B1b[32];
    float LnG[32];
    float LnB[32];
    float B2b[64];
    float Bias[81];
};
// total = 38423 floats = 153,692 B  (<= 160 KiB gfx950 LDS)

__global__ __launch_bounds__(BLOCK_, 2)
void wattn_fused(const float* __restrict__ x,
                 const float* __restrict__ w_qkv,
                 const float* __restrict__ pe,
                 const float* __restrict__ w1,
                 const float* __restrict__ b1,
                 const float* __restrict__ lng,
                 const float* __restrict__ lnb,
                 const float* __restrict__ w2,
                 const float* __restrict__ b2,
                 float* __restrict__ out)
{
    __shared__ Smem sm;
    const int t = threadIdx.x;

    // ---------------- stage weights (once per block) ----------------
    for (int idx = t; idx < OC_ * DIM_; idx += BLOCK_)
        sm.W[(idx >> 6) * PW_ + (idx & 63)] = w_qkv[idx];
    for (int idx = t; idx < 32 * DIM_; idx += BLOCK_)
        sm.W1[(idx >> 6) * PW1_ + (idx & 63)] = w1[idx];
    for (int idx = t; idx < 64 * 32; idx += BLOCK_)
        sm.W2[(idx >> 5) * PW2_ + (idx & 31)] = w2[idx];
    if (t < 32) { sm.B1b[t] = b1[t]; sm.LnG[t] = lng[t]; sm.LnB[t] = lnb[t]; }
    if (t >= 64 && t < 128) sm.B2b[t - 64] = b2[t - 64];
    if (t >= 128 && t < 128 + 81) {
        int ij = t - 128;
        int i = ij / 9, j = ij % 9;
        int r0 = (j / 3) - (i / 3) + 2;   // in [0,4]
        int r1 = (j % 3) - (i % 3) + 2;
        sm.Bias[ij] = pe[r0 * 5 + r1];
    }
    __syncthreads();

    for (int bi = 0; bi < BPB_; ++bi) {
        const size_t b = (size_t)blockIdx.x * BPB_ + bi;
        const float* xb = x + b * (P_ * DIM_);

        // ---- stage x[b] : 81x64 -> sm.X (float2, pad 66) ----
        for (int idx = t; idx < P_ * DIM_ / 2; idx += BLOCK_) {
            int p  = idx >> 5;        // /32 float2 per row
            int c2 = idx & 31;
            float2 v = ((const float2*)xb)[idx];
            *(float2*)&sm.X[p * PX_ + c2 * 2] = v;
        }
        __syncthreads();

        // ---- phase A: qkv[p][o] = x[p][:] . w_qkv[o][:]  (tiles 4p x 8o) ----
        if (t < 504) {
            int po = t / 24;          // 0..20  -> p0 = 4*po
            int oo = t % 24;          // o_j = oo + 24*j, j=0..7
            int p0 = po * 4;
            float acc[4][8];
            #pragma unroll
            for (int ii = 0; ii < 4; ++ii)
                #pragma unroll
                for (int jj = 0; jj < 8; ++jj) acc[ii][jj] = 0.f;
            int pidx[4];
            #pragma unroll
            for (int ii = 0; ii < 4; ++ii) pidx[ii] = min(p0 + ii, P_ - 1);
            #pragma unroll 4
            for (int c2 = 0; c2 < 32; ++c2) {
                float2 xv[4];
                #pragma unroll
                for (int ii = 0; ii < 4; ++ii)
                    xv[ii] = *(const float2*)&sm.X[pidx[ii] * PX_ + c2 * 2];
                #pragma unroll
                for (int jj = 0; jj < 8; ++jj) {
                    int o = oo + jj * 24;
                    float2 wv = *(const float2*)&sm.W[o * PW_ + c2 * 2];
                    #pragma unroll
                    for (int ii = 0; ii < 4; ++ii)
                        acc[ii][jj] += xv[ii].x * wv.x + xv[ii].y * wv.y;
                }
            }
            #pragma unroll
            for (int ii = 0; ii < 4; ++ii) {
                int p = p0 + ii;
                if (p < P_) {
                    #pragma unroll
                    for (int jj = 0; jj < 8; ++jj)
                        sm.QKV[p * PQ_ + oo + jj * 24] = acc[ii][jj];
                }
            }
        }
        __syncthreads();

        // ---- zero canvas (overlays sm.X; x is dead now) ----
        for (int idx = t; idx < P_ * PX_; idx += BLOCK_) sm.X[idx] = 0.f;
        __syncthreads();

        // ---- phase C: attention rows + scrambled scatter ----
        for (int task = t; task < 576; task += BLOCK_) {
            int w   = task / 36;          // window 0..15
            int rem = task % 36;
            int h   = rem / 9;            // head
            int i   = rem % 9;            // query pos in window
            int g0 = w >> 2, g1 = w & 3;
            int r0 = 2 * g0, c0 = 2 * g1;
            int posq = (r0 + i / 3) * 9 + (c0 + i % 3);
            const float* qrow = &sm.QKV[posq * PQ_ + h * HD_];
            float q[16];
            #pragma unroll
            for (int d4 = 0; d4 < 4; ++d4) {
                float4 v = *(const float4*)&qrow[d4 * 4];
                q[d4*4+0] = v.x; q[d4*4+1] = v.y; q[d4*4+2] = v.z; q[d4*4+3] = v.w;
            }
            float l[9];
            float mx = -1e30f;
            #pragma unroll
            for (int j = 0; j < 9; ++j) {
                int posk = (r0 + j / 3) * 9 + (c0 + j % 3);
                const float* krow = &sm.QKV[posk * PQ_ + 64 + h * HD_];
                float s = 0.f;
                #pragma unroll
                for (int d4 = 0; d4 < 4; ++d4) {
                    float4 v = *(const float4*)&krow[d4 * 4];
                    s += q[d4*4+0]*v.x + q[d4*4+1]*v.y + q[d4*4+2]*v.z + q[d4*4+3]*v.w;
                }
                l[j] = s * 0.25f + sm.Bias[i * 9 + j];
                mx = fmaxf(mx, l[j]);
            }
            float sum = 0.f;
            #pragma unroll
            for (int j = 0; j < 9; ++j) { l[j] = __expf(l[j] - mx); sum += l[j]; }
            float inv = 1.f / sum;
            float o[16];
            #pragma unroll
            for (int d = 0; d < 16; ++d) o[d] = 0.f;
            #pragma unroll
            for (int j = 0; j < 9; ++j) {
                float a = l[j] * inv;
                int posv = (r0 + j / 3) * 9 + (c0 + j % 3);
                const float* vrow = &sm.QKV[posv * PQ_ + 128 + h * HD_];
                #pragma unroll
                for (int d4 = 0; d4 < 4; ++d4) {
                    float4 v = *(const float4*)&vrow[d4 * 4];
                    o[d4*4+0] += a * v.x; o[d4*4+1] += a * v.y;
                    o[d4*4+2] += a * v.z; o[d4*4+3] += a * v.w;
                }
            }
            // scatter: idx576 = i*64 + h*16 + d ; c = idx576/9 ; (p0,p1) = idx576%9
            int base576 = i * 64 + h * 16;
            #pragma unroll
            for (int d = 0; d < 16; ++d) {
                int idx576 = base576 + d;
                int c  = idx576 / 9;
                int r  = idx576 - 9 * c;
                int sp0 = r / 3;
                int sp1 = r - 3 * sp0;
                int row = (r0 + sp0) * 9 + (c0 + sp1);
                atomicAdd(&sm.X[row * PX_ + c], o[d]);
            }
        }
        __syncthreads();

        // ---- phase E: h1 = canvas @ w1^T + b1 ; LN ; gelu(exact) ----
        if (t < 324) {                 // 81 rows x 4 threads, 8 channels each
            int row = t >> 2;
            int m0  = (t & 3) * 8;
            float h1v[8];
            #pragma unroll
            for (int jj = 0; jj < 8; ++jj) h1v[jj] = sm.B1b[m0 + jj];
            #pragma unroll 4
            for (int c2 = 0; c2 < 32; ++c2) {
                float2 cv = *(const float2*)&sm.X[row * PX_ + c2 * 2];
                #pragma unroll
                for (int jj = 0; jj < 8; ++jj) {
                    float2 wv = *(const float2*)&sm.W1[(m0 + jj) * PW1_ + c2 * 2];
                    h1v[jj] += cv.x * wv.x + cv.y * wv.y;
                }
            }
            float s1 = 0.f, s2 = 0.f;
            #pragma unroll
            for (int jj = 0; jj < 8; ++jj) { s1 += h1v[jj]; s2 += h1v[jj] * h1v[jj]; }
            s1 += __shfl_xor(s1, 1); s2 += __shfl_xor(s2, 1);
            s1 += __shfl_xor(s1, 2); s2 += __shfl_xor(s2, 2);
            float mean = s1 * (1.f / 32.f);
            float var  = s2 * (1.f / 32.f) - mean * mean;
            float rs   = rsqrtf(var + 1e-5f);
            #pragma unroll
            for (int jj = 0; jj < 8; ++jj) {
                float xn = (h1v[jj] - mean) * rs * sm.LnG[m0 + jj] + sm.LnB[m0 + jj];
                float g  = 0.5f * xn * (1.f + erff(xn * 0.70710678118654752f));
                sm.QKV[row * PH_ + m0 + jj] = g;   // H1 overlays dead QKV
            }
        }
        __syncthreads();

        // ---- phase F: out = h1g @ w2^T + b2 -> global ----
        float* sH1 = sm.QKV;
        for (int idx = t; idx < P_ * 16; idx += BLOCK_) {
            int p  = idx >> 4;
            int o0 = (idx & 15) * 4;
            float a0 = sm.B2b[o0], a1 = sm.B2b[o0+1], a2 = sm.B2b[o0+2], a3 = sm.B2b[o0+3];
            #pragma unroll 4
            for (int m2 = 0; m2 < 16; ++m2) {
                float2 hv  = *(const float2*)&sH1[p * PH_ + m2 * 2];
                float2 w0v = *(const float2*)&sm.W2[(o0+0) * PW2_ + m2 * 2];
                float2 w1v = *(const float2*)&sm.W2[(o0+1) * PW2_ + m2 * 2];
                float2 w2v = *(const float2*)&sm.W2[(o0+2) * PW2_ + m2 * 2];
                float2 w3v = *(const float2*)&sm.W2[(o0+3) * PW2_ + m2 * 2];
                a0 += hv.x * w0v.x + hv.y * w0v.y;
                a1 += hv.x * w1v.x + hv.y * w1v.y;
                a2 += hv.x * w2v.x + hv.y * w2v.y;
                a3 += hv.x * w3v.x + hv.y * w3v.y;
            }
            float4 res = make_float4(a0, a1, a2, a3);
            *(float4*)&out[(b * P_ + p) * DIM_ + o0] = res;
        }
        __syncthreads();   // protect H1 (QKV region) before next batch's phase A
    }
}

extern "C" void kernel_launch(void* const* d_in, const int* in_sizes, int n_in,
                              void* d_out, int out_size, void* d_ws, size_t ws_size,
                              hipStream_t stream) {
    const float* x     = (const float*)d_in[0];
    const float* w_qkv = (const float*)d_in[1];
    const float* pe    = (const float*)d_in[2];
    const float* w1    = (const float*)d_in[3];
    const float* b1    = (const float*)d_in[4];
    const float* lng   = (const float*)d_in[5];
    const float* lnb   = (const float*)d_in[6];
    const float* w2    = (const float*)d_in[7];
    const float* b2    = (const float*)d_in[8];
    float* outp = (float*)d_out;

    wattn_fused<<<dim3(NBLK_), dim3(BLOCK_), 0, stream>>>(
        x, w_qkv, pe, w1, b1, lng, lnb, w2, b2, outp);
}

// Round 2
// 640.823 us; speedup vs baseline: 2.1369x; 2.1369x over previous
//
#include <hip/hip_runtime.h>
#include <math.h>

#define BLOCK_ 512
#define BPB_   8
#define NBLK_  (8192/BPB_)   // 1024 blocks

typedef __bf16 bf16x8 __attribute__((ext_vector_type(8)));
typedef float  f32x4  __attribute__((ext_vector_type(4)));
typedef unsigned short us8 __attribute__((ext_vector_type(8)));

// element strides (chosen: 16B-aligned rows, <=2-way bank aliasing)
#define XS_  72    // Xbuf bf16 stride   (144B = 36 banks -> 2-way)
#define WQS_ 72    // Wq bf16
#define QKS_ 136   // QK bf16            (272B -> 2-way)
#define VS_  68    // V fp32             (272B -> 2-way)
#define CS_  68    // canvas fp32
#define W1S_ 72
#define W2S_ 40
#define HGS_ 40    // H1g bf16 (80B = 20 banks -> 2-way)

struct alignas(16) Smem {
    unsigned short Xb[2][96*XS_];   // 27648 B  (double-buffered x, bf16)
    unsigned short Wq[192*WQS_];    // 27648 B
    unsigned short QK[96*QKS_];     // 26112 B  (q cols 0-63, k cols 64-127; H1g overlays)
    float          Vf[96*VS_];      // 26112 B  (v kept fp32)
    float          Cv[96*CS_];      // 26112 B  (atomic canvas fp32)
    unsigned short W1[32*W1S_];     //  4608 B
    unsigned short W2[64*W2S_];     //  5120 B
    float Bias[81];
    float B1v[32], LnG[32], LnB[32], B2v[64];
};  // total 144,324 B  (< 160 KiB)

__device__ __forceinline__ unsigned short f2bf(float f) {
    union { float f; unsigned u; } v; v.f = f;
    unsigned r = v.u + 0x7FFFu + ((v.u >> 16) & 1u);   // RNE
    return (unsigned short)(r >> 16);
}
__device__ __forceinline__ float bf2f(unsigned short b) {
    union { float f; unsigned u; } v; v.u = ((unsigned)b) << 16;
    return v.f;
}
__device__ __forceinline__ us8 pack8(float4 a, float4 b) {
    us8 r;
    r[0]=f2bf(a.x); r[1]=f2bf(a.y); r[2]=f2bf(a.z); r[3]=f2bf(a.w);
    r[4]=f2bf(b.x); r[5]=f2bf(b.y); r[6]=f2bf(b.z); r[7]=f2bf(b.w);
    return r;
}
__device__ __forceinline__ f32x4 mfma16(us8 a, us8 b, f32x4 c) {
    return __builtin_amdgcn_mfma_f32_16x16x32_bf16(
        __builtin_bit_cast(bf16x8, a), __builtin_bit_cast(bf16x8, b), c, 0, 0, 0);
}

__global__ __launch_bounds__(BLOCK_, 2)
void wattn_mfma(const float* __restrict__ x, const float* __restrict__ w_qkv,
                const float* __restrict__ pe, const float* __restrict__ w1,
                const float* __restrict__ b1, const float* __restrict__ lng,
                const float* __restrict__ lnb, const float* __restrict__ w2,
                const float* __restrict__ b2, float* __restrict__ out)
{
    __shared__ Smem sm;
    const int t = threadIdx.x;
    const int wv = t >> 6, lane = t & 63;
    const int lrow = lane & 15;
    const int lk   = (lane >> 4) * 8;   // A/B frag k-offset within a 32-step
    const int g4   = (lane >> 4) * 4;   // D row-group

    // ---------------- prologue: weights + bias + zeros + x[0] ----------------
    for (int task = t; task < 192*8; task += BLOCK_) {
        int p = task >> 3, c8 = task & 7;
        const float4* src = (const float4*)(w_qkv + p*64 + c8*8);
        *(us8*)&sm.Wq[p*WQS_ + c8*8] = pack8(src[0], src[1]);
    }
    for (int task = t; task < 32*8; task += BLOCK_) {
        int p = task >> 3, c8 = task & 7;
        const float4* src = (const float4*)(w1 + p*64 + c8*8);
        *(us8*)&sm.W1[p*W1S_ + c8*8] = pack8(src[0], src[1]);
    }
    for (int task = t; task < 64*4; task += BLOCK_) {
        int p = task >> 2, c8 = task & 3;
        const float4* src = (const float4*)(w2 + p*32 + c8*8);
        *(us8*)&sm.W2[p*W2S_ + c8*8] = pack8(src[0], src[1]);
    }
    if (t < 32) { sm.B1v[t]=b1[t]; sm.LnG[t]=lng[t]; sm.LnB[t]=lnb[t]; }
    if (t >= 64 && t < 128) sm.B2v[t-64] = b2[t-64];
    if (t >= 128 && t < 209) {
        int ij = t-128; int i = ij/9, j = ij%9;
        sm.Bias[ij] = pe[((j/3)-(i/3)+2)*5 + ((j%3)-(i%3)+2)];
    }
    for (int idx = t; idx < 96*CS_; idx += BLOCK_) sm.Cv[idx] = 0.f;
    for (int idx = t; idx < 2*15*XS_; idx += BLOCK_) {       // zero A-pad rows 81..95
        int bsel = idx / (15*XS_); int rem = idx % (15*XS_);
        sm.Xb[bsel][(81 + rem/XS_)*XS_ + rem%XS_] = 0;
    }
    {
        const float* xb = x + (size_t)blockIdx.x * BPB_ * (81*64);
        for (int task = t; task < 648; task += BLOCK_) {
            int p = task >> 3, c8 = task & 7;
            const float4* src = (const float4*)(xb + p*64 + c8*8);
            *(us8*)&sm.Xb[0][p*XS_ + c8*8] = pack8(src[0], src[1]);
        }
    }
    __syncthreads();

    for (int bi = 0; bi < BPB_; ++bi) {
        const int cur = bi & 1;
        const size_t b = (size_t)blockIdx.x * BPB_ + bi;

        // -------- issue prefetch of next batch's x (consumed end of phase C) --------
        float4 pA0, pA1, pB0, pB1;
        const bool hasPF = (bi + 1 < BPB_);
        const bool hasPF2 = hasPF && (t < 136);
        if (hasPF) {
            const float4* xn = (const float4*)(x + (b+1)*(81*64));
            pA0 = xn[t*2]; pA1 = xn[t*2+1];
            if (hasPF2) { pB0 = xn[(512+t)*2]; pB1 = xn[(512+t)*2+1]; }
        }

        // -------- phase A: qkv = x @ Wqkv^T via MFMA (6m x 12n x 2k tiles) --------
        {
            const int mg = wv >> 2, ng = wv & 3;
            us8 af[3][2];
            #pragma unroll
            for (int mi = 0; mi < 3; ++mi)
                #pragma unroll
                for (int k = 0; k < 2; ++k)
                    af[mi][k] = *(const us8*)&sm.Xb[cur][(mg*48 + mi*16 + lrow)*XS_ + k*32 + lk];
            #pragma unroll
            for (int ni = 0; ni < 3; ++ni) {
                const int n = ng*3 + ni;
                f32x4 acc[3] = {{0,0,0,0},{0,0,0,0},{0,0,0,0}};
                #pragma unroll
                for (int k = 0; k < 2; ++k) {
                    us8 bf = *(const us8*)&sm.Wq[(n*16 + lrow)*WQS_ + k*32 + lk];
                    #pragma unroll
                    for (int mi = 0; mi < 3; ++mi)
                        acc[mi] = mfma16(af[mi][k], bf, acc[mi]);
                }
                #pragma unroll
                for (int mi = 0; mi < 3; ++mi) {
                    const int row0 = mg*48 + mi*16 + g4;
                    if (n < 8) {
                        #pragma unroll
                        for (int r = 0; r < 4; ++r)
                            sm.QK[(row0+r)*QKS_ + n*16 + lrow] = f2bf(acc[mi][r]);
                    } else {
                        #pragma unroll
                        for (int r = 0; r < 4; ++r)
                            sm.Vf[(row0+r)*VS_ + (n-8)*16 + lrow] = acc[mi][r];
                    }
                }
            }
        }
        __syncthreads();

        // -------- phase C: 576 attention tasks (w,h,i) + scrambled scatter --------
        for (int task = t; task < 576; task += BLOCK_) {
            int w = task/36, rem = task%36, h = rem/9, i = rem%9;
            int r0 = (w>>2)*2, c0 = (w&3)*2;
            int posq = (r0 + i/3)*9 + (c0 + i%3);
            float q[16];
            {
                us8 u0 = *(const us8*)&sm.QK[posq*QKS_ + h*16];
                us8 u1 = *(const us8*)&sm.QK[posq*QKS_ + h*16 + 8];
                #pragma unroll
                for (int jj=0;jj<8;++jj){ q[jj]=bf2f(u0[jj]); q[8+jj]=bf2f(u1[jj]); }
            }
            float l[9]; float mx = -1e30f;
            #pragma unroll
            for (int j = 0; j < 9; ++j) {
                int posk = (r0 + j/3)*9 + (c0 + j%3);
                us8 u0 = *(const us8*)&sm.QK[posk*QKS_ + 64 + h*16];
                us8 u1 = *(const us8*)&sm.QK[posk*QKS_ + 64 + h*16 + 8];
                float s = 0.f;
                #pragma unroll
                for (int jj=0;jj<8;++jj) s += q[jj]*bf2f(u0[jj]) + q[8+jj]*bf2f(u1[jj]);
                l[j] = s*0.25f + sm.Bias[i*9+j];
                mx = fmaxf(mx, l[j]);
            }
            float ssum = 0.f;
            #pragma unroll
            for (int j=0;j<9;++j){ l[j]=__expf(l[j]-mx); ssum+=l[j]; }
            float inv = 1.f/ssum;
            float o[16];
            #pragma unroll
            for (int d=0; d<16; ++d) o[d]=0.f;
            #pragma unroll
            for (int j = 0; j < 9; ++j) {
                float a = l[j]*inv;
                int posv = (r0 + j/3)*9 + (c0 + j%3);
                const float* vr = &sm.Vf[posv*VS_ + h*16];
                #pragma unroll
                for (int d4=0; d4<4; ++d4) {
                    float4 v = *(const float4*)&vr[d4*4];
                    o[d4*4+0]+=a*v.x; o[d4*4+1]+=a*v.y; o[d4*4+2]+=a*v.z; o[d4*4+3]+=a*v.w;
                }
            }
            int base576 = i*64 + h*16;
            #pragma unroll
            for (int d=0; d<16; ++d) {
                int idx = base576 + d;
                int c = idx/9, r = idx - 9*c;
                int row = (r0 + r/3)*9 + (c0 + r%3);
                atomicAdd(&sm.Cv[row*CS_ + c], o[d]);
            }
        }
        // write prefetched x into the other buffer (T14 write-late)
        if (hasPF) {
            int p = t >> 3, c8 = t & 7;
            *(us8*)&sm.Xb[cur^1][p*XS_ + c8*8] = pack8(pA0, pA1);
            if (hasPF2) {
                int task = 512 + t; p = task >> 3; c8 = task & 7;
                *(us8*)&sm.Xb[cur^1][p*XS_ + c8*8] = pack8(pB0, pB1);
            }
        }
        __syncthreads();

        // -------- phase G: MLP1 MFMA (canvas f32 -> bf16 frags) + in-reg LN + gelu --------
        if (wv < 6) {
            const int m = wv;
            us8 aF[2];
            #pragma unroll
            for (int k = 0; k < 2; ++k) {
                const float* cp = &sm.Cv[(m*16+lrow)*CS_ + k*32 + lk];
                float4 c0v = *(const float4*)cp;
                float4 c1v = *(const float4*)(cp+4);
                aF[k] = pack8(c0v, c1v);
            }
            f32x4 a0 = {0,0,0,0}, a1 = {0,0,0,0};
            #pragma unroll
            for (int k = 0; k < 2; ++k) {
                us8 b0 = *(const us8*)&sm.W1[lrow*W1S_ + k*32 + lk];
                us8 b1f = *(const us8*)&sm.W1[(16+lrow)*W1S_ + k*32 + lk];
                a0 = mfma16(aF[k], b0, a0);
                a1 = mfma16(aF[k], b1f, a1);
            }
            float bb0 = sm.B1v[lrow],    bb1 = sm.B1v[16+lrow];
            float gg0 = sm.LnG[lrow],    gg1 = sm.LnG[16+lrow];
            float ee0 = sm.LnB[lrow],    ee1 = sm.LnB[16+lrow];
            float v0[4], v1[4], srow[4], qrow[4];
            #pragma unroll
            for (int r=0;r<4;++r) {
                v0[r] = a0[r] + bb0; v1[r] = a1[r] + bb1;
                srow[r] = v0[r] + v1[r];
                qrow[r] = v0[r]*v0[r] + v1[r]*v1[r];
            }
            #pragma unroll
            for (int mask = 1; mask <= 8; mask <<= 1) {
                #pragma unroll
                for (int r=0;r<4;++r) {
                    srow[r] += __shfl_xor(srow[r], mask);
                    qrow[r] += __shfl_xor(qrow[r], mask);
                }
            }
            unsigned short* H1g = sm.QK;   // overlays dead QK
            #pragma unroll
            for (int r=0;r<4;++r) {
                float mean = srow[r]*(1.f/32.f);
                float var  = qrow[r]*(1.f/32.f) - mean*mean;
                float rs   = rsqrtf(var + 1e-5f);
                int row = m*16 + g4 + r;
                float xn0 = (v0[r]-mean)*rs*gg0 + ee0;
                float xn1 = (v1[r]-mean)*rs*gg1 + ee1;
                float ge0 = 0.5f*xn0*(1.f + erff(xn0*0.70710678118654752f));
                float ge1 = 0.5f*xn1*(1.f + erff(xn1*0.70710678118654752f));
                H1g[row*HGS_ + lrow]      = f2bf(ge0);
                H1g[row*HGS_ + 16 + lrow] = f2bf(ge1);
            }
        }
        __syncthreads();

        // -------- phase J: MLP2 MFMA -> global store; re-zero canvas --------
        {
            const unsigned short* H1g = sm.QK;
            #pragma unroll
            for (int ti = 0; ti < 3; ++ti) {
                int ft = wv*3 + ti;
                int m = ft >> 2, n = ft & 3;
                us8 aH = *(const us8*)&H1g[(m*16+lrow)*HGS_ + lk];
                us8 bW = *(const us8*)&sm.W2[(n*16+lrow)*W2S_ + lk];
                f32x4 acc = {0,0,0,0};
                acc = mfma16(aH, bW, acc);
                float bb = sm.B2v[n*16+lrow];
                int row0 = m*16 + g4;
                #pragma unroll
                for (int r=0;r<4;++r) {
                    int row = row0 + r;
                    if (row < 81)
                        out[(b*81 + (size_t)row)*64 + n*16 + lrow] = acc[r] + bb;
                }
            }
        }
        for (int idx = t; idx < 96*CS_; idx += BLOCK_) sm.Cv[idx] = 0.f;
        __syncthreads();
    }
}

extern "C" void kernel_launch(void* const* d_in, const int* in_sizes, int n_in,
                              void* d_out, int out_size, void* d_ws, size_t ws_size,
                              hipStream_t stream) {
    const float* x     = (const float*)d_in[0];
    const float* w_qkv = (const float*)d_in[1];
    const float* pe    = (const float*)d_in[2];
    const float* w1    = (const float*)d_in[3];
    const float* b1    = (const float*)d_in[4];
    const float* lng   = (const float*)d_in[5];
    const float* lnb   = (const float*)d_in[6];
    const float* w2    = (const float*)d_in[7];
    const float* b2    = (const float*)d_in[8];
    float* outp = (float*)d_out;

    wattn_mfma<<<dim3(NBLK_), dim3(BLOCK_), 0, stream>>>(
        x, w_qkv, pe, w1, b1, lng, lnb, w2, b2, outp);
}